// Round 1
// baseline (216.160 us; speedup 1.0000x reference)
//
#include <hip/hip_runtime.h>
#include <stdint.h>

// SRU layer fused pipeline:
//  1) cvt:   w_ufr f32 -> bf16
//  2) ln:    LayerNorm rows (T*B=16384, D=1024) -> x_norm bf16
//  3) gemm:  x_norm[16384,1024] @ W^T[1024,3072] -> ufr bf16 (hardsigmoid
//            applied to f/r column regions in epilogue)
//  4) scan1: per-chunk (A = prod f, B) linear-recurrence composition
//  5) scan2: sequential scan over 32 chunks -> chunk-start c, c_last
//  6) scan3: within-chunk recurrence + softsign + output mix + residual

#define T_SEQ 2048
#define BATCH 8
#define DIM 1024
#define M_SZ (T_SEQ * BATCH)   // 16384
#define N_SZ (3 * DIM)         // 3072
#define K_SZ DIM               // 1024
#define NCHUNK 32
#define CLEN (T_SEQ / NCHUNK)  // 64

#define BM 128
#define BN 128
#define BK 32

typedef __attribute__((ext_vector_type(8))) __bf16 bf16x8;
typedef __attribute__((ext_vector_type(4))) float f32x4;

__device__ __forceinline__ unsigned short f2bf(float f) {
  unsigned int u = __float_as_uint(f);
  u += 0x7FFFu + ((u >> 16) & 1u);   // round-to-nearest-even
  return (unsigned short)(u >> 16);
}
__device__ __forceinline__ float bf2f(unsigned short s) {
  return __uint_as_float(((unsigned int)s) << 16);
}
__device__ __forceinline__ void gload16(const void* g, void* l) {
  __builtin_amdgcn_global_load_lds(
      (__attribute__((address_space(1))) void*)const_cast<void*>(g),
      (__attribute__((address_space(3))) void*)l, 16, 0, 0);
}

// ---------------- 1) weight f32 -> bf16 ----------------
__global__ __launch_bounds__(256) void cvt_kernel(const float* __restrict__ w,
                                                  unsigned short* __restrict__ wb) {
  const int i = blockIdx.x * 256 + threadIdx.x;
  const float4 v = reinterpret_cast<const float4*>(w)[i];
  ushort4 o;
  o.x = f2bf(v.x); o.y = f2bf(v.y); o.z = f2bf(v.z); o.w = f2bf(v.w);
  reinterpret_cast<ushort4*>(wb)[i] = o;
}

// ---------------- 2) LayerNorm ----------------
__global__ __launch_bounds__(256) void ln_kernel(const float* __restrict__ x,
                                                 const float* __restrict__ gamma,
                                                 const float* __restrict__ beta,
                                                 unsigned short* __restrict__ xn) {
  const int row = blockIdx.x;
  const int tid = threadIdx.x;
  const float4 v = reinterpret_cast<const float4*>(x + (size_t)row * DIM)[tid];
  float s = v.x + v.y + v.z + v.w;
  float q = v.x * v.x + v.y * v.y + v.z * v.z + v.w * v.w;
#pragma unroll
  for (int off = 32; off > 0; off >>= 1) {
    s += __shfl_down(s, off);
    q += __shfl_down(q, off);
  }
  __shared__ float sbuf[8];
  const int wv = tid >> 6, ln = tid & 63;
  if (ln == 0) { sbuf[wv] = s; sbuf[4 + wv] = q; }
  __syncthreads();
  s = sbuf[0] + sbuf[1] + sbuf[2] + sbuf[3];
  q = sbuf[4] + sbuf[5] + sbuf[6] + sbuf[7];
  const float mu = s * (1.0f / DIM);
  const float rstd = rsqrtf(q * (1.0f / DIM) - mu * mu + 1e-5f);
  const float4 g = reinterpret_cast<const float4*>(gamma)[tid];
  const float4 b = reinterpret_cast<const float4*>(beta)[tid];
  ushort4 o;
  o.x = f2bf((v.x - mu) * rstd * g.x + b.x);
  o.y = f2bf((v.y - mu) * rstd * g.y + b.y);
  o.z = f2bf((v.z - mu) * rstd * g.z + b.z);
  o.w = f2bf((v.w - mu) * rstd * g.w + b.w);
  reinterpret_cast<ushort4*>(xn + (size_t)row * DIM)[tid] = o;
}

// ---------------- 3) GEMM: C[m,n] = sum_k A[m,k] * W[n,k], bf16 MFMA ----------------
// m97-style: 128x128 tile, BK=32, 4 waves (2x2), each wave 64x64 = 4x4 frags
// of 16x16. global_load_lds width 16, linear LDS [rows][BK].
__global__ __launch_bounds__(256) void gemm_kernel(const unsigned short* __restrict__ A,
                                                   const unsigned short* __restrict__ W,
                                                   unsigned short* __restrict__ C) {
  __shared__ unsigned short smA[BM * BK];
  __shared__ unsigned short smB[BN * BK];
  const int tid = threadIdx.x;
  const int lane = tid & 63;
  const int wid = tid >> 6;
  const int wm = wid >> 1, wn = wid & 1;
  const int bm0 = blockIdx.y * BM, bn0 = blockIdx.x * BN;

  // staging map: wave wid covers rows [wid*16, wid*16+16) and +64 of each tile;
  // lane l -> row = base + l/4, col8 = (l%4)*8  (matches LDS linear dest order)
  const int ldr = wid * 16 + (lane >> 2);
  const int ldc = (lane & 3) * 8;
  const unsigned short* gA0 = A + (size_t)(bm0 + ldr) * K_SZ + ldc;
  const unsigned short* gA1 = gA0 + (size_t)64 * K_SZ;
  const unsigned short* gB0 = W + (size_t)(bn0 + ldr) * K_SZ + ldc;
  const unsigned short* gB1 = gB0 + (size_t)64 * K_SZ;
  unsigned short* sA0 = &smA[(wid * 16) * BK];
  unsigned short* sA1 = &smA[(64 + wid * 16) * BK];
  unsigned short* sB0 = &smB[(wid * 16) * BK];
  unsigned short* sB1 = &smB[(64 + wid * 16) * BK];

  f32x4 acc[4][4] = {};
  const int fr = lane & 15;        // fragment row (A) / col (B) / col (C)
  const int ko = (lane >> 4) * 8;  // fragment k offset

  for (int kt = 0; kt < K_SZ / BK; ++kt) {
    gload16(gA0, sA0);
    gload16(gA1, sA1);
    gload16(gB0, sB0);
    gload16(gB1, sB1);
    gA0 += BK; gA1 += BK; gB0 += BK; gB1 += BK;
    __syncthreads();   // drains vmcnt (global_load_lds) + barrier
    bf16x8 af[4], bfr[4];
#pragma unroll
    for (int i = 0; i < 4; i++)
      af[i] = *(const bf16x8*)&smA[(wm * 64 + i * 16 + fr) * BK + ko];
#pragma unroll
    for (int j = 0; j < 4; j++)
      bfr[j] = *(const bf16x8*)&smB[(wn * 64 + j * 16 + fr) * BK + ko];
#pragma unroll
    for (int i = 0; i < 4; i++)
#pragma unroll
      for (int j = 0; j < 4; j++)
        acc[i][j] = __builtin_amdgcn_mfma_f32_16x16x32_bf16(af[i], bfr[j], acc[i][j], 0, 0, 0);
    __syncthreads();   // protect LDS before next stage
  }

  // epilogue: C/D layout col = lane&15, row = (lane>>4)*4 + reg  [m89-verified]
  const int gate = (bn0 >= DIM);  // whole 128-col tile lies in u, f, or r region
  const int fq = lane >> 4;
#pragma unroll
  for (int i = 0; i < 4; i++) {
#pragma unroll
    for (int j = 0; j < 4; j++) {
      const int col = bn0 + wn * 64 + j * 16 + fr;
      size_t base = (size_t)(bm0 + wm * 64 + i * 16 + fq * 4) * N_SZ + col;
#pragma unroll
      for (int r = 0; r < 4; r++) {
        float v = acc[i][j][r];
        if (gate) v = fminf(fmaxf(v * (1.0f / 6.0f) + 0.5f, 0.0f), 1.0f);
        C[base + (size_t)r * N_SZ] = f2bf(v);
      }
    }
  }
}

// ---------------- 4) per-chunk recurrence composition ----------------
__global__ __launch_bounds__(256) void scan1_kernel(const unsigned short* __restrict__ ufr,
                                                    float* __restrict__ Ac,
                                                    float* __restrict__ Bc) {
  const int lin = blockIdx.x * 256 + threadIdx.x;   // NCHUNK*B*D
  const int d = lin & (DIM - 1);
  const int b = (lin >> 10) & (BATCH - 1);
  const int g = lin >> 13;
  const unsigned short* p = ufr + (size_t)(g * CLEN) * (BATCH * N_SZ) + (size_t)b * N_SZ + d;
  float Aa = 1.0f, Bb = 0.0f;
#pragma unroll 8
  for (int t = 0; t < CLEN; t++) {
    const float u = bf2f(p[0]);
    const float f = bf2f(p[DIM]);      // already hardsigmoid'ed
    Aa *= f;
    Bb = f * Bb + (1.0f - f) * u;
    p += BATCH * N_SZ;
  }
  Ac[lin] = Aa;
  Bc[lin] = Bb;
}

// ---------------- 5) scan over chunks ----------------
__global__ __launch_bounds__(256) void scan2_kernel(const float* __restrict__ Ac,
                                                    const float* __restrict__ Bc,
                                                    const float* __restrict__ c0,
                                                    float* __restrict__ cstart,
                                                    float* __restrict__ clast) {
  const int lin = blockIdx.x * 256 + threadIdx.x;   // B*D = 8192
  float c = c0[lin];
#pragma unroll
  for (int g = 0; g < NCHUNK; g++) {
    cstart[g * (BATCH * DIM) + lin] = c;
    c = Ac[g * (BATCH * DIM) + lin] * c + Bc[g * (BATCH * DIM) + lin];
  }
  clast[lin] = c;
}

// ---------------- 6) within-chunk recurrence + epilogue ----------------
__global__ __launch_bounds__(256) void scan3_kernel(const unsigned short* __restrict__ ufr,
                                                    const unsigned short* __restrict__ xn,
                                                    const float* __restrict__ x,
                                                    const float* __restrict__ cstart,
                                                    float* __restrict__ out) {
  const int lin = blockIdx.x * 256 + threadIdx.x;
  const int d = lin & (DIM - 1);
  const int b = (lin >> 10) & (BATCH - 1);
  const int g = lin >> 13;
  float c = cstart[g * (BATCH * DIM) + b * DIM + d];
  const unsigned short* p = ufr + (size_t)(g * CLEN) * (BATCH * N_SZ) + (size_t)b * N_SZ + d;
  size_t xo = (size_t)(g * CLEN) * (BATCH * DIM) + (size_t)b * DIM + d;
#pragma unroll 4
  for (int t = 0; t < CLEN; t++) {
    const float u = bf2f(p[0]);
    const float f = bf2f(p[DIM]);
    const float r = bf2f(p[2 * DIM]);
    c = f * c + (1.0f - f) * u;
    const float ts = c / (1.0f + fabsf(c));   // softsign
    const float xv = bf2f(xn[xo]);
    out[xo] = x[xo] + r * ts + (1.0f - r) * xv;
    p += BATCH * N_SZ;
    xo += BATCH * DIM;
  }
}

extern "C" void kernel_launch(void* const* d_in, const int* in_sizes, int n_in,
                              void* d_out, int out_size, void* d_ws, size_t ws_size,
                              hipStream_t stream) {
  const float* x = (const float*)d_in[0];
  const float* c0 = (const float*)d_in[1];
  const float* w = (const float*)d_in[2];
  const float* gamma = (const float*)d_in[3];
  const float* beta = (const float*)d_in[4];
  float* out = (float*)d_out;
  float* clast = out + (size_t)M_SZ * DIM;   // second output, flat-concatenated

  // workspace layout (total ~143.7 MB)
  char* ws = (char*)d_ws;
  unsigned short* xn = (unsigned short*)ws;                        //  33,554,432 B
  unsigned short* ufr = (unsigned short*)(ws + 33554432ull);       // 100,663,296 B
  float* Ac = (float*)(ws + 134217728ull);                         //   1,048,576 B
  float* Bc = (float*)(ws + 135266304ull);                         //   1,048,576 B
  float* cst = (float*)(ws + 136314880ull);                        //   1,048,576 B
  unsigned short* wb = (unsigned short*)(ws + 137363456ull);       //   6,291,456 B

  cvt_kernel<<<(N_SZ * K_SZ / 4) / 256, 256, 0, stream>>>(w, wb);
  ln_kernel<<<M_SZ, 256, 0, stream>>>(x, gamma, beta, xn);
  dim3 ggrid(N_SZ / BN, M_SZ / BM);
  gemm_kernel<<<ggrid, 256, 0, stream>>>(xn, wb, ufr);
  scan1_kernel<<<(NCHUNK * BATCH * DIM) / 256, 256, 0, stream>>>(ufr, Ac, Bc);
  scan2_kernel<<<(BATCH * DIM) / 256, 256, 0, stream>>>(Ac, Bc, c0, cst, clast);
  scan3_kernel<<<(NCHUNK * BATCH * DIM) / 256, 256, 0, stream>>>(ufr, xn, x, cst, out);
}

// Round 2
// 210.749 us; speedup vs baseline: 1.0257x; 1.0257x over previous
//
#include <hip/hip_runtime.h>
#include <stdint.h>

// SRU layer fused pipeline:
//  1) cvt:   w_ufr f32 -> bf16
//  2) ln:    LayerNorm rows (T*B=16384, D=1024) -> x_norm bf16
//  3) gemm:  256x256-tile, 4-deep LDS pipeline, counted vmcnt (never drains
//            in main loop), raw s_barrier. bf16 MFMA, f32 acc. hardsigmoid
//            fused for f/r column regions.
//  4) scan1: per-chunk (A = prod f, B) linear-recurrence composition
//  5) scan2: sequential scan over 32 chunks -> chunk-start c, c_last
//  6) scan3: within-chunk recurrence + softsign + output mix + residual

#define T_SEQ 2048
#define BATCH 8
#define DIM 1024
#define M_SZ (T_SEQ * BATCH)   // 16384
#define N_SZ (3 * DIM)         // 3072
#define K_SZ DIM               // 1024
#define NCHUNK 32
#define CLEN (T_SEQ / NCHUNK)  // 64

#define GBM 256
#define GBN 256
#define GBK 32
#define NKT (K_SZ / GBK)       // 32 K-tiles

typedef __attribute__((ext_vector_type(8))) __bf16 bf16x8;
typedef __attribute__((ext_vector_type(4))) float f32x4;

__device__ __forceinline__ unsigned short f2bf(float f) {
  unsigned int u = __float_as_uint(f);
  u += 0x7FFFu + ((u >> 16) & 1u);   // round-to-nearest-even
  return (unsigned short)(u >> 16);
}
__device__ __forceinline__ float bf2f(unsigned short s) {
  return __uint_as_float(((unsigned int)s) << 16);
}
__device__ __forceinline__ void gload16(const void* g, void* l) {
  __builtin_amdgcn_global_load_lds(
      (__attribute__((address_space(1))) void*)const_cast<void*>(g),
      (__attribute__((address_space(3))) void*)l, 16, 0, 0);
}

// ---------------- 1) weight f32 -> bf16 ----------------
__global__ __launch_bounds__(256) void cvt_kernel(const float* __restrict__ w,
                                                  unsigned short* __restrict__ wb) {
  const int i = blockIdx.x * 256 + threadIdx.x;
  const float4 v = reinterpret_cast<const float4*>(w)[i];
  ushort4 o;
  o.x = f2bf(v.x); o.y = f2bf(v.y); o.z = f2bf(v.z); o.w = f2bf(v.w);
  reinterpret_cast<ushort4*>(wb)[i] = o;
}

// ---------------- 2) LayerNorm ----------------
__global__ __launch_bounds__(256) void ln_kernel(const float* __restrict__ x,
                                                 const float* __restrict__ gamma,
                                                 const float* __restrict__ beta,
                                                 unsigned short* __restrict__ xn) {
  const int row = blockIdx.x;
  const int tid = threadIdx.x;
  const float4 v = reinterpret_cast<const float4*>(x + (size_t)row * DIM)[tid];
  float s = v.x + v.y + v.z + v.w;
  float q = v.x * v.x + v.y * v.y + v.z * v.z + v.w * v.w;
#pragma unroll
  for (int off = 32; off > 0; off >>= 1) {
    s += __shfl_down(s, off);
    q += __shfl_down(q, off);
  }
  __shared__ float sbuf[8];
  const int wv = tid >> 6, ln = tid & 63;
  if (ln == 0) { sbuf[wv] = s; sbuf[4 + wv] = q; }
  __syncthreads();
  s = sbuf[0] + sbuf[1] + sbuf[2] + sbuf[3];
  q = sbuf[4] + sbuf[5] + sbuf[6] + sbuf[7];
  const float mu = s * (1.0f / DIM);
  const float rstd = rsqrtf(q * (1.0f / DIM) - mu * mu + 1e-5f);
  const float4 g = reinterpret_cast<const float4*>(gamma)[tid];
  const float4 b = reinterpret_cast<const float4*>(beta)[tid];
  ushort4 o;
  o.x = f2bf((v.x - mu) * rstd * g.x + b.x);
  o.y = f2bf((v.y - mu) * rstd * g.y + b.y);
  o.z = f2bf((v.z - mu) * rstd * g.z + b.z);
  o.w = f2bf((v.w - mu) * rstd * g.w + b.w);
  reinterpret_cast<ushort4*>(xn + (size_t)row * DIM)[tid] = o;
}

// ---------------- 3) GEMM: C[m,n] = sum_k A[m,k] * W[n,k], bf16 MFMA ----------------
// 256x256 tile, BK=32, 512 threads (8 waves, 2Mx4N), per-wave 128x64 output.
// 4 LDS buffers (128 KiB total): prefetch depth 3, s_waitcnt vmcnt(8) steady
// state (2 tiles in flight), ONE raw s_barrier per K-step, no drain in loop.
__global__ __launch_bounds__(512) void gemm_kernel(const unsigned short* __restrict__ A,
                                                   const unsigned short* __restrict__ W,
                                                   unsigned short* __restrict__ C) {
  // A region: [0, 4*256*32) elems ; B region: [32768, 65536)
  __shared__ unsigned short smem[2 * 4 * GBM * GBK];   // 131072 B
  const int tid = threadIdx.x;
  const int lane = tid & 63;
  const int wid = tid >> 6;                 // 0..7
  const int wm = wid >> 2, wn = wid & 3;    // 2 x 4 wave grid
  const int bm0 = blockIdx.y * GBM, bn0 = blockIdx.x * GBN;

  // staging map: wave wid owns rows [wid*32, wid*32+32) of each 256-row tile,
  // as 2 gload16 instrs of 16 rows (1024 B) each. lane l -> row +l/4, colslot l%4.
  const int stgRow = wid * 32 + (lane >> 2);
  const int stgCol = (lane & 3) * 8;
  const unsigned short* gA = A + (size_t)(bm0 + stgRow) * K_SZ + stgCol;
  const unsigned short* gB = W + (size_t)(bn0 + stgRow) * K_SZ + stgCol;
  unsigned short* sAb = smem + wid * 32 * GBK;             // wave-uniform LDS base
  unsigned short* sBb = smem + 4 * GBM * GBK + wid * 32 * GBK;

#define STAGE(bufi, t) do {                                        \
    const size_t ko_ = (size_t)(t) * GBK;                          \
    unsigned short* sa_ = sAb + (bufi) * (GBM * GBK);              \
    unsigned short* sb_ = sBb + (bufi) * (GBN * GBK);              \
    gload16(gA + ko_, sa_);                                        \
    gload16(gA + ko_ + (size_t)16 * K_SZ, sa_ + 16 * GBK);         \
    gload16(gB + ko_, sb_);                                        \
    gload16(gB + ko_ + (size_t)16 * K_SZ, sb_ + 16 * GBK);         \
  } while (0)

  f32x4 acc[8][4] = {};
  const int fr = lane & 15;          // fragment row (A) / col (B,C)
  const int ko8 = (lane >> 4) * 8;   // fragment k element offset

  // prologue: tiles 0,1,2 -> buffers 0,1,2 (12 loads/thread)
  STAGE(0, 0);
  STAGE(1, 1);
  STAGE(2, 2);
  asm volatile("s_waitcnt vmcnt(8)" ::: "memory");   // tile 0 landed
  __builtin_amdgcn_s_barrier();
  asm volatile("" ::: "memory");

  for (int kt = 0; kt < NKT; ++kt) {
    const int cur = kt & 3;
    if (kt < NKT - 3) STAGE((kt + 3) & 3, kt + 3);   // buffer reads done at iter kt-1

    const unsigned short* sa = smem + cur * (GBM * GBK);
    const unsigned short* sb = smem + 4 * GBM * GBK + cur * (GBN * GBK);
    bf16x8 af[8], bf[4];
#pragma unroll
    for (int i = 0; i < 8; i++)
      af[i] = *(const bf16x8*)&sa[(wm * 128 + i * 16 + fr) * GBK + ko8];
#pragma unroll
    for (int j = 0; j < 4; j++)
      bf[j] = *(const bf16x8*)&sb[(wn * 64 + j * 16 + fr) * GBK + ko8];

    __builtin_amdgcn_s_setprio(1);
#pragma unroll
    for (int i = 0; i < 8; i++)
#pragma unroll
      for (int j = 0; j < 4; j++)
        acc[i][j] = __builtin_amdgcn_mfma_f32_16x16x32_bf16(af[i], bf[j], acc[i][j], 0, 0, 0);
    __builtin_amdgcn_s_setprio(0);

    // wait tile kt+1 landed: allow tiles kt+2,kt+3 (8 loads) in flight
    if (kt < NKT - 3)       asm volatile("s_waitcnt vmcnt(8)" ::: "memory");
    else if (kt == NKT - 3) asm volatile("s_waitcnt vmcnt(4)" ::: "memory");
    else if (kt == NKT - 2) asm volatile("s_waitcnt vmcnt(0)" ::: "memory");
    if (kt < NKT - 1) {
      __builtin_amdgcn_s_barrier();
      asm volatile("" ::: "memory");
    }
  }
#undef STAGE

  // epilogue: C/D layout col = lane&15, row = (lane>>4)*4 + reg  [m89-verified]
  const int gate = (bn0 >= DIM);  // whole 256-col tile lies in u, or in f/r region
  const int fq = lane >> 4;
#pragma unroll
  for (int i = 0; i < 8; i++) {
#pragma unroll
    for (int j = 0; j < 4; j++) {
      const int col = bn0 + wn * 64 + j * 16 + fr;
      size_t base = (size_t)(bm0 + wm * 128 + i * 16 + fq * 4) * N_SZ + col;
#pragma unroll
      for (int r = 0; r < 4; r++) {
        float v = acc[i][j][r];
        if (gate) v = fminf(fmaxf(v * (1.0f / 6.0f) + 0.5f, 0.0f), 1.0f);
        C[base + (size_t)r * N_SZ] = f2bf(v);
      }
    }
  }
}

// ---------------- 4) per-chunk recurrence composition ----------------
__global__ __launch_bounds__(256) void scan1_kernel(const unsigned short* __restrict__ ufr,
                                                    float* __restrict__ Ac,
                                                    float* __restrict__ Bc) {
  const int lin = blockIdx.x * 256 + threadIdx.x;   // NCHUNK*B*D
  const int d = lin & (DIM - 1);
  const int b = (lin >> 10) & (BATCH - 1);
  const int g = lin >> 13;
  const unsigned short* p = ufr + (size_t)(g * CLEN) * (BATCH * N_SZ) + (size_t)b * N_SZ + d;
  float Aa = 1.0f, Bb = 0.0f;
#pragma unroll 8
  for (int t = 0; t < CLEN; t++) {
    const float u = bf2f(p[0]);
    const float f = bf2f(p[DIM]);      // already hardsigmoid'ed
    Aa *= f;
    Bb = f * Bb + (1.0f - f) * u;
    p += BATCH * N_SZ;
  }
  Ac[lin] = Aa;
  Bc[lin] = Bb;
}

// ---------------- 5) scan over chunks ----------------
__global__ __launch_bounds__(256) void scan2_kernel(const float* __restrict__ Ac,
                                                    const float* __restrict__ Bc,
                                                    const float* __restrict__ c0,
                                                    float* __restrict__ cstart,
                                                    float* __restrict__ clast) {
  const int lin = blockIdx.x * 256 + threadIdx.x;   // B*D = 8192
  float c = c0[lin];
#pragma unroll
  for (int g = 0; g < NCHUNK; g++) {
    cstart[g * (BATCH * DIM) + lin] = c;
    c = Ac[g * (BATCH * DIM) + lin] * c + Bc[g * (BATCH * DIM) + lin];
  }
  clast[lin] = c;
}

// ---------------- 6) within-chunk recurrence + epilogue ----------------
__global__ __launch_bounds__(256) void scan3_kernel(const unsigned short* __restrict__ ufr,
                                                    const unsigned short* __restrict__ xn,
                                                    const float* __restrict__ x,
                                                    const float* __restrict__ cstart,
                                                    float* __restrict__ out) {
  const int lin = blockIdx.x * 256 + threadIdx.x;
  const int d = lin & (DIM - 1);
  const int b = (lin >> 10) & (BATCH - 1);
  const int g = lin >> 13;
  float c = cstart[g * (BATCH * DIM) + b * DIM + d];
  const unsigned short* p = ufr + (size_t)(g * CLEN) * (BATCH * N_SZ) + (size_t)b * N_SZ + d;
  size_t xo = (size_t)(g * CLEN) * (BATCH * DIM) + (size_t)b * DIM + d;
#pragma unroll 4
  for (int t = 0; t < CLEN; t++) {
    const float u = bf2f(p[0]);
    const float f = bf2f(p[DIM]);
    const float r = bf2f(p[2 * DIM]);
    c = f * c + (1.0f - f) * u;
    const float ts = c / (1.0f + fabsf(c));   // softsign
    const float xv = bf2f(xn[xo]);
    out[xo] = x[xo] + r * ts + (1.0f - r) * xv;
    p += BATCH * N_SZ;
    xo += BATCH * DIM;
  }
}

extern "C" void kernel_launch(void* const* d_in, const int* in_sizes, int n_in,
                              void* d_out, int out_size, void* d_ws, size_t ws_size,
                              hipStream_t stream) {
  const float* x = (const float*)d_in[0];
  const float* c0 = (const float*)d_in[1];
  const float* w = (const float*)d_in[2];
  const float* gamma = (const float*)d_in[3];
  const float* beta = (const float*)d_in[4];
  float* out = (float*)d_out;
  float* clast = out + (size_t)M_SZ * DIM;   // second output, flat-concatenated

  // workspace layout (total ~143.7 MB)
  char* ws = (char*)d_ws;
  unsigned short* xn = (unsigned short*)ws;                        //  33,554,432 B
  unsigned short* ufr = (unsigned short*)(ws + 33554432ull);       // 100,663,296 B
  float* Ac = (float*)(ws + 134217728ull);                         //   1,048,576 B
  float* Bc = (float*)(ws + 135266304ull);                         //   1,048,576 B
  float* cst = (float*)(ws + 136314880ull);                        //   1,048,576 B
  unsigned short* wb = (unsigned short*)(ws + 137363456ull);       //   6,291,456 B

  cvt_kernel<<<(N_SZ * K_SZ / 4) / 256, 256, 0, stream>>>(w, wb);
  ln_kernel<<<M_SZ, 256, 0, stream>>>(x, gamma, beta, xn);
  dim3 ggrid(N_SZ / GBN, M_SZ / GBM);
  gemm_kernel<<<ggrid, 512, 0, stream>>>(xn, wb, ufr);
  scan1_kernel<<<(NCHUNK * BATCH * DIM) / 256, 256, 0, stream>>>(ufr, Ac, Bc);
  scan2_kernel<<<(BATCH * DIM) / 256, 256, 0, stream>>>(Ac, Bc, c0, cst, clast);
  scan3_kernel<<<(NCHUNK * BATCH * DIM) / 256, 256, 0, stream>>>(ufr, xn, x, cst, out);
}

// Round 3
// 206.836 us; speedup vs baseline: 1.0451x; 1.0189x over previous
//
#include <hip/hip_runtime.h>
#include <stdint.h>

// SRU layer fused pipeline:
//  1) cvt:   w_ufr f32 -> bf16
//  2) ln:    LayerNorm rows (T*B=16384, D=1024) -> x_norm bf16
//  3) gemm:  256x256-tile, 4-deep LDS pipeline, counted vmcnt, raw s_barrier,
//            T2 XOR slot-swizzle (2 lanes/bank). bf16 MFMA, f32 acc.
//            hardsigmoid fused for f/r column regions.
//  4) scan1: per-chunk (A = prod f, B) linear-recurrence composition
//  5) scan2: sequential scan over 32 chunks -> chunk-start c, c_last
//  6) scan3: within-chunk recurrence + softsign + output mix + residual

#define T_SEQ 2048
#define BATCH 8
#define DIM 1024
#define M_SZ (T_SEQ * BATCH)   // 16384
#define N_SZ (3 * DIM)         // 3072
#define K_SZ DIM               // 1024
#define NCHUNK 32
#define CLEN (T_SEQ / NCHUNK)  // 64

#define GBM 256
#define GBN 256
#define GBK 32
#define NKT (K_SZ / GBK)       // 32 K-tiles

typedef __attribute__((ext_vector_type(8))) __bf16 bf16x8;
typedef __attribute__((ext_vector_type(4))) float f32x4;

__device__ __forceinline__ unsigned short f2bf(float f) {
  unsigned int u = __float_as_uint(f);
  u += 0x7FFFu + ((u >> 16) & 1u);   // round-to-nearest-even
  return (unsigned short)(u >> 16);
}
__device__ __forceinline__ float bf2f(unsigned short s) {
  return __uint_as_float(((unsigned int)s) << 16);
}
__device__ __forceinline__ void gload16(const void* g, void* l) {
  __builtin_amdgcn_global_load_lds(
      (__attribute__((address_space(1))) void*)const_cast<void*>(g),
      (__attribute__((address_space(3))) void*)l, 16, 0, 0);
}

// ---------------- 1) weight f32 -> bf16 ----------------
__global__ __launch_bounds__(256) void cvt_kernel(const float* __restrict__ w,
                                                  unsigned short* __restrict__ wb) {
  const int i = blockIdx.x * 256 + threadIdx.x;
  const float4 v = reinterpret_cast<const float4*>(w)[i];
  ushort4 o;
  o.x = f2bf(v.x); o.y = f2bf(v.y); o.z = f2bf(v.z); o.w = f2bf(v.w);
  reinterpret_cast<ushort4*>(wb)[i] = o;
}

// ---------------- 2) LayerNorm ----------------
__global__ __launch_bounds__(256) void ln_kernel(const float* __restrict__ x,
                                                 const float* __restrict__ gamma,
                                                 const float* __restrict__ beta,
                                                 unsigned short* __restrict__ xn) {
  const int row = blockIdx.x;
  const int tid = threadIdx.x;
  const float4 v = reinterpret_cast<const float4*>(x + (size_t)row * DIM)[tid];
  float s = v.x + v.y + v.z + v.w;
  float q = v.x * v.x + v.y * v.y + v.z * v.z + v.w * v.w;
#pragma unroll
  for (int off = 32; off > 0; off >>= 1) {
    s += __shfl_down(s, off);
    q += __shfl_down(q, off);
  }
  __shared__ float sbuf[8];
  const int wv = tid >> 6, ln = tid & 63;
  if (ln == 0) { sbuf[wv] = s; sbuf[4 + wv] = q; }
  __syncthreads();
  s = sbuf[0] + sbuf[1] + sbuf[2] + sbuf[3];
  q = sbuf[4] + sbuf[5] + sbuf[6] + sbuf[7];
  const float mu = s * (1.0f / DIM);
  const float rstd = rsqrtf(q * (1.0f / DIM) - mu * mu + 1e-5f);
  const float4 g = reinterpret_cast<const float4*>(gamma)[tid];
  const float4 b = reinterpret_cast<const float4*>(beta)[tid];
  ushort4 o;
  o.x = f2bf((v.x - mu) * rstd * g.x + b.x);
  o.y = f2bf((v.y - mu) * rstd * g.y + b.y);
  o.z = f2bf((v.z - mu) * rstd * g.z + b.z);
  o.w = f2bf((v.w - mu) * rstd * g.w + b.w);
  reinterpret_cast<ushort4*>(xn + (size_t)row * DIM)[tid] = o;
}

// ---------------- 3) GEMM: C[m,n] = sum_k A[m,k] * W[n,k], bf16 MFMA ----------------
// 256x256 tile, BK=32, 512 threads (8 waves, 2Mx4N), per-wave 128x64 output.
// 4 LDS buffers (128 KiB): depth-3 prefetch, s_waitcnt vmcnt(8) steady state,
// one raw s_barrier per K-step.
// T2 swizzle: LDS[row][slot] holds global[row][slot ^ ((row>>1)&3)] (16B slots
// within each 64B row). global_load_lds writes linearly, so the permutation is
// applied to the per-lane GLOBAL source address; ds_read applies the same XOR.
// Bank = 16*(row&1) + 4*(slot^((row>>1)&3)) -> exactly 2 lanes/bank (free).
__global__ __launch_bounds__(512) void gemm_kernel(const unsigned short* __restrict__ A,
                                                   const unsigned short* __restrict__ W,
                                                   unsigned short* __restrict__ C) {
  // A region: [0, 4*256*32) elems ; B region: [32768, 65536)
  __shared__ unsigned short smem[2 * 4 * GBM * GBK];   // 131072 B
  const int tid = threadIdx.x;
  const int lane = tid & 63;
  const int wid = tid >> 6;                 // 0..7
  const int wm = wid >> 2, wn = wid & 3;    // 2 x 4 wave grid
  const int bm0 = blockIdx.y * GBM, bn0 = blockIdx.x * GBN;

  // staging map: wave wid owns rows [wid*32, wid*32+32) of each 256-row tile,
  // as 2 gload16 instrs of 16 rows (1024 B) each. lane l -> LDS row +l/4,
  // LDS slot l%4; global col-slot pre-swizzled: (l&3) ^ ((l>>3)&3)
  // (= (l&3) ^ ((row>>1)&3) since row = wid*32 + h*16 + (l>>2)).
  const int stgRow = wid * 32 + (lane >> 2);
  const int stgCol = ((lane & 3) ^ ((lane >> 3) & 3)) * 8;
  const unsigned short* gA = A + (size_t)(bm0 + stgRow) * K_SZ + stgCol;
  const unsigned short* gB = W + (size_t)(bn0 + stgRow) * K_SZ + stgCol;
  unsigned short* sAb = smem + wid * 32 * GBK;             // wave-uniform LDS base
  unsigned short* sBb = smem + 4 * GBM * GBK + wid * 32 * GBK;

#define STAGE(bufi, t) do {                                        \
    const size_t ko_ = (size_t)(t) * GBK;                          \
    unsigned short* sa_ = sAb + (bufi) * (GBM * GBK);              \
    unsigned short* sb_ = sBb + (bufi) * (GBN * GBK);              \
    gload16(gA + ko_, sa_);                                        \
    gload16(gA + ko_ + (size_t)16 * K_SZ, sa_ + 16 * GBK);         \
    gload16(gB + ko_, sb_);                                        \
    gload16(gB + ko_ + (size_t)16 * K_SZ, sb_ + 16 * GBK);         \
  } while (0)

  f32x4 acc[8][4] = {};
  const int fr = lane & 15;          // fragment row (A) / col (B,C)
  // swizzled k-slot element offset: slot = lane>>4, XOR (fr>>1)&3.
  // ((R>>1)&3) == ((fr>>1)&3) for all fragment rows R = base16*16 + fr.
  const int ko8 = ((lane >> 4) ^ ((fr >> 1) & 3)) * 8;

  // prologue: tiles 0,1,2 -> buffers 0,1,2 (12 loads/thread)
  STAGE(0, 0);
  STAGE(1, 1);
  STAGE(2, 2);
  asm volatile("s_waitcnt vmcnt(8)" ::: "memory");   // tile 0 landed
  __builtin_amdgcn_s_barrier();
  asm volatile("" ::: "memory");

  for (int kt = 0; kt < NKT; ++kt) {
    const int cur = kt & 3;
    if (kt < NKT - 3) STAGE((kt + 3) & 3, kt + 3);   // buffer reads done at iter kt-1

    const unsigned short* sa = smem + cur * (GBM * GBK);
    const unsigned short* sb = smem + 4 * GBM * GBK + cur * (GBN * GBK);
    bf16x8 af[8], bf[4];
#pragma unroll
    for (int i = 0; i < 8; i++)
      af[i] = *(const bf16x8*)&sa[(wm * 128 + i * 16 + fr) * GBK + ko8];
#pragma unroll
    for (int j = 0; j < 4; j++)
      bf[j] = *(const bf16x8*)&sb[(wn * 64 + j * 16 + fr) * GBK + ko8];

    __builtin_amdgcn_s_setprio(1);
#pragma unroll
    for (int i = 0; i < 8; i++)
#pragma unroll
      for (int j = 0; j < 4; j++)
        acc[i][j] = __builtin_amdgcn_mfma_f32_16x16x32_bf16(af[i], bf[j], acc[i][j], 0, 0, 0);
    __builtin_amdgcn_s_setprio(0);

    // wait tile kt+1 landed: allow tiles kt+2,kt+3 (8 loads) in flight
    if (kt < NKT - 3)       asm volatile("s_waitcnt vmcnt(8)" ::: "memory");
    else if (kt == NKT - 3) asm volatile("s_waitcnt vmcnt(4)" ::: "memory");
    else if (kt == NKT - 2) asm volatile("s_waitcnt vmcnt(0)" ::: "memory");
    if (kt < NKT - 1) {
      __builtin_amdgcn_s_barrier();
      asm volatile("" ::: "memory");
    }
  }
#undef STAGE

  // epilogue: C/D layout col = lane&15, row = (lane>>4)*4 + reg  [m89-verified]
  const int gate = (bn0 >= DIM);  // whole 256-col tile lies in u, or in f/r region
  const int fq = lane >> 4;
#pragma unroll
  for (int i = 0; i < 8; i++) {
#pragma unroll
    for (int j = 0; j < 4; j++) {
      const int col = bn0 + wn * 64 + j * 16 + fr;
      size_t base = (size_t)(bm0 + wm * 128 + i * 16 + fq * 4) * N_SZ + col;
#pragma unroll
      for (int r = 0; r < 4; r++) {
        float v = acc[i][j][r];
        if (gate) v = fminf(fmaxf(v * (1.0f / 6.0f) + 0.5f, 0.0f), 1.0f);
        C[base + (size_t)r * N_SZ] = f2bf(v);
      }
    }
  }
}

// ---------------- 4) per-chunk recurrence composition ----------------
__global__ __launch_bounds__(256) void scan1_kernel(const unsigned short* __restrict__ ufr,
                                                    float* __restrict__ Ac,
                                                    float* __restrict__ Bc) {
  const int lin = blockIdx.x * 256 + threadIdx.x;   // NCHUNK*B*D
  const int d = lin & (DIM - 1);
  const int b = (lin >> 10) & (BATCH - 1);
  const int g = lin >> 13;
  const unsigned short* p = ufr + (size_t)(g * CLEN) * (BATCH * N_SZ) + (size_t)b * N_SZ + d;
  float Aa = 1.0f, Bb = 0.0f;
#pragma unroll 8
  for (int t = 0; t < CLEN; t++) {
    const float u = bf2f(p[0]);
    const float f = bf2f(p[DIM]);      // already hardsigmoid'ed
    Aa *= f;
    Bb = f * Bb + (1.0f - f) * u;
    p += BATCH * N_SZ;
  }
  Ac[lin] = Aa;
  Bc[lin] = Bb;
}

// ---------------- 5) scan over chunks ----------------
__global__ __launch_bounds__(256) void scan2_kernel(const float* __restrict__ Ac,
                                                    const float* __restrict__ Bc,
                                                    const float* __restrict__ c0,
                                                    float* __restrict__ cstart,
                                                    float* __restrict__ clast) {
  const int lin = blockIdx.x * 256 + threadIdx.x;   // B*D = 8192
  float c = c0[lin];
#pragma unroll
  for (int g = 0; g < NCHUNK; g++) {
    cstart[g * (BATCH * DIM) + lin] = c;
    c = Ac[g * (BATCH * DIM) + lin] * c + Bc[g * (BATCH * DIM) + lin];
  }
  clast[lin] = c;
}

// ---------------- 6) within-chunk recurrence + epilogue ----------------
__global__ __launch_bounds__(256) void scan3_kernel(const unsigned short* __restrict__ ufr,
                                                    const unsigned short* __restrict__ xn,
                                                    const float* __restrict__ x,
                                                    const float* __restrict__ cstart,
                                                    float* __restrict__ out) {
  const int lin = blockIdx.x * 256 + threadIdx.x;
  const int d = lin & (DIM - 1);
  const int b = (lin >> 10) & (BATCH - 1);
  const int g = lin >> 13;
  float c = cstart[g * (BATCH * DIM) + b * DIM + d];
  const unsigned short* p = ufr + (size_t)(g * CLEN) * (BATCH * N_SZ) + (size_t)b * N_SZ + d;
  size_t xo = (size_t)(g * CLEN) * (BATCH * DIM) + (size_t)b * DIM + d;
#pragma unroll 4
  for (int t = 0; t < CLEN; t++) {
    const float u = bf2f(p[0]);
    const float f = bf2f(p[DIM]);
    const float r = bf2f(p[2 * DIM]);
    c = f * c + (1.0f - f) * u;
    const float ts = c / (1.0f + fabsf(c));   // softsign
    const float xv = bf2f(xn[xo]);
    out[xo] = x[xo] + r * ts + (1.0f - r) * xv;
    p += BATCH * N_SZ;
    xo += BATCH * DIM;
  }
}

extern "C" void kernel_launch(void* const* d_in, const int* in_sizes, int n_in,
                              void* d_out, int out_size, void* d_ws, size_t ws_size,
                              hipStream_t stream) {
  const float* x = (const float*)d_in[0];
  const float* c0 = (const float*)d_in[1];
  const float* w = (const float*)d_in[2];
  const float* gamma = (const float*)d_in[3];
  const float* beta = (const float*)d_in[4];
  float* out = (float*)d_out;
  float* clast = out + (size_t)M_SZ * DIM;   // second output, flat-concatenated

  // workspace layout (total ~143.7 MB)
  char* ws = (char*)d_ws;
  unsigned short* xn = (unsigned short*)ws;                        //  33,554,432 B
  unsigned short* ufr = (unsigned short*)(ws + 33554432ull);       // 100,663,296 B
  float* Ac = (float*)(ws + 134217728ull);                         //   1,048,576 B
  float* Bc = (float*)(ws + 135266304ull);                         //   1,048,576 B
  float* cst = (float*)(ws + 136314880ull);                        //   1,048,576 B
  unsigned short* wb = (unsigned short*)(ws + 137363456ull);       //   6,291,456 B

  cvt_kernel<<<(N_SZ * K_SZ / 4) / 256, 256, 0, stream>>>(w, wb);
  ln_kernel<<<M_SZ, 256, 0, stream>>>(x, gamma, beta, xn);
  dim3 ggrid(N_SZ / GBN, M_SZ / GBM);
  gemm_kernel<<<ggrid, 512, 0, stream>>>(xn, wb, ufr);
  scan1_kernel<<<(NCHUNK * BATCH * DIM) / 256, 256, 0, stream>>>(ufr, Ac, Bc);
  scan2_kernel<<<(BATCH * DIM) / 256, 256, 0, stream>>>(Ac, Bc, c0, cst, clast);
  scan3_kernel<<<(NCHUNK * BATCH * DIM) / 256, 256, 0, stream>>>(ufr, xn, x, cst, out);
}